// Round 2
// baseline (202.482 us; speedup 1.0000x reference)
//
#include <hip/hip_runtime.h>
#include <hip/hip_bf16.h>

#define B_  2
#define S_  4096
#define H_  8
#define HD_ 64
#define D_  512

using bf16x8 = __attribute__((ext_vector_type(8))) short;  // 8 bf16 in 4 VGPRs
using f32x4  = __attribute__((ext_vector_type(4))) float;

__device__ __forceinline__ unsigned short f2bf(float f) {
    unsigned int u = __float_as_uint(f);
    u += 0x7FFFu + ((u >> 16) & 1u);   // RNE
    return (unsigned short)(u >> 16);
}

// ---------------------------------------------------------------------------
// Kernel 1: per-head QKV projection.  grid (S/64, B*H), block 256 (4 waves)
// K[bh][s][e], Q[bh][s][e] (pre-scaled by 0.125*log2e), Vt[bh][e][s]  (bf16)
// ---------------------------------------------------------------------------
__global__ __launch_bounds__(256) void proj_kernel(
    const float* __restrict__ x,  const float* __restrict__ yy,
    const float* __restrict__ Wk, const float* __restrict__ bk,
    const float* __restrict__ Wq, const float* __restrict__ bq,
    const float* __restrict__ Wv, const float* __restrict__ bv,
    unsigned short* __restrict__ Qw, unsigned short* __restrict__ Kw,
    unsigned short* __restrict__ Vt)
{
    __shared__ __attribute__((aligned(16))) unsigned short xs[64][72];
    __shared__ __attribute__((aligned(16))) unsigned short ys[64][72];
    __shared__ __attribute__((aligned(16))) unsigned short wtk[64][72];
    __shared__ __attribute__((aligned(16))) unsigned short wtq[64][72];
    __shared__ __attribute__((aligned(16))) unsigned short wtv[64][72];
    __shared__ __attribute__((aligned(16))) unsigned short vtl[64][72];

    const int t  = threadIdx.x;
    const int s0 = blockIdx.x * 64;
    const int bh = blockIdx.y;
    const int b  = bh >> 3, h = bh & 7;

    // stage x,y tiles [64 rows][64 cols] as bf16 (rows padded to 72)
    #pragma unroll
    for (int i = 0; i < 4; ++i) {
        int id = t + 256 * i;           // 1024 float4 chunks
        int row = id >> 4, c4 = id & 15;
        size_t ga = ((size_t)(b * S_ + s0 + row)) * D_ + h * HD_ + c4 * 4;
        float4 xv = *(const float4*)(x + ga);
        float4 yv = *(const float4*)(yy + ga);
        unsigned int xl = f2bf(xv.x) | ((unsigned int)f2bf(xv.y) << 16);
        unsigned int xh = f2bf(xv.z) | ((unsigned int)f2bf(xv.w) << 16);
        unsigned int yl = f2bf(yv.x) | ((unsigned int)f2bf(yv.y) << 16);
        unsigned int yh = f2bf(yv.z) | ((unsigned int)f2bf(yv.w) << 16);
        *(uint2*)&xs[row][c4 * 4] = make_uint2(xl, xh);
        *(uint2*)&ys[row][c4 * 4] = make_uint2(yl, yh);
    }
    // stage weights TRANSPOSED: wt[e][d] so B-fragments are contiguous in k=d
    #pragma unroll
    for (int i = 0; i < 4; ++i) {
        int id = t + 256 * i;           // 1024 float4 chunks
        int dd = id >> 4, e4 = id & 15;
        size_t wa = (size_t)(h * HD_ + dd) * HD_ + e4 * 4;
        float4 wk4 = *(const float4*)(Wk + wa);
        float4 wq4 = *(const float4*)(Wq + wa);
        float4 wv4 = *(const float4*)(Wv + wa);
        wtk[e4*4+0][dd] = f2bf(wk4.x); wtk[e4*4+1][dd] = f2bf(wk4.y);
        wtk[e4*4+2][dd] = f2bf(wk4.z); wtk[e4*4+3][dd] = f2bf(wk4.w);
        wtq[e4*4+0][dd] = f2bf(wq4.x); wtq[e4*4+1][dd] = f2bf(wq4.y);
        wtq[e4*4+2][dd] = f2bf(wq4.z); wtq[e4*4+3][dd] = f2bf(wq4.w);
        wtv[e4*4+0][dd] = f2bf(wv4.x); wtv[e4*4+1][dd] = f2bf(wv4.y);
        wtv[e4*4+2][dd] = f2bf(wv4.z); wtv[e4*4+3][dd] = f2bf(wv4.w);
    }
    __syncthreads();

    const int lane = t & 63, w = t >> 6;
    const int g = lane >> 4, lq = lane & 15;

    bf16x8 ax[2], ay[2];
    #pragma unroll
    for (int kk = 0; kk < 2; ++kk) {
        ax[kk] = *(const bf16x8*)&xs[w*16 + lq][kk*32 + g*8];
        ay[kk] = *(const bf16x8*)&ys[w*16 + lq][kk*32 + g*8];
    }

    f32x4 ak[4], aq[4], av[4];
    #pragma unroll
    for (int n = 0; n < 4; ++n) { ak[n] = (f32x4)0.f; aq[n] = (f32x4)0.f; av[n] = (f32x4)0.f; }

    #pragma unroll
    for (int n = 0; n < 4; ++n) {
        #pragma unroll
        for (int kk = 0; kk < 2; ++kk) {
            bf16x8 bk_ = *(const bf16x8*)&wtk[n*16 + lq][kk*32 + g*8];
            ak[n] = __builtin_amdgcn_mfma_f32_16x16x32_bf16(ax[kk], bk_, ak[n], 0, 0, 0);
            bf16x8 bq_ = *(const bf16x8*)&wtq[n*16 + lq][kk*32 + g*8];
            aq[n] = __builtin_amdgcn_mfma_f32_16x16x32_bf16(ay[kk], bq_, aq[n], 0, 0, 0);
            bf16x8 bv_ = *(const bf16x8*)&wtv[n*16 + lq][kk*32 + g*8];
            av[n] = __builtin_amdgcn_mfma_f32_16x16x32_bf16(ax[kk], bv_, av[n], 0, 0, 0);
        }
    }

    const float cscale = 0.125f * 1.44269504088896340736f;  // fold 1/sqrt(64) and log2(e) into Q
    #pragma unroll
    for (int n = 0; n < 4; ++n) {
        int e = n*16 + lq;
        float bkv = bk[h*HD_ + e], bqv = bq[h*HD_ + e], bvv = bv[h*HD_ + e];
        #pragma unroll
        for (int r = 0; r < 4; ++r) {
            int srow = w*16 + g*4 + r;                 // C layout: row=(lane>>4)*4+reg
            size_t o = ((size_t)bh * S_ + s0 + srow) * HD_ + e;
            Kw[o] = f2bf(ak[n][r] + bkv);
            Qw[o] = f2bf((aq[n][r] + bqv) * cscale);
            vtl[e][srow] = f2bf(av[n][r] + bvv);       // transpose V via LDS
        }
    }
    __syncthreads();
    // coalesced store of V^T tile: Vt[bh][e][s0..s0+63]
    #pragma unroll
    for (int i = 0; i < 2; ++i) {
        int id = t + 256 * i;           // 512 16B chunks
        int e = id >> 3, c = id & 7;
        bf16x8 v = *(const bf16x8*)&vtl[e][c*8];
        *(bf16x8*)(Vt + ((size_t)bh * HD_ + e) * S_ + s0 + c*8) = v;
    }
}

// ---------------------------------------------------------------------------
// Kernel 2: flash attention. grid (S/64, B*H), block 256 (4 waves x 16 q-rows)
// Swapped QK^T: st = mfma(K_tile, Q^T) -> lane owns one q-row's P values.
// ---------------------------------------------------------------------------
__global__ __launch_bounds__(256) void attn_kernel(
    const unsigned short* __restrict__ Qw, const unsigned short* __restrict__ Kw,
    const unsigned short* __restrict__ Vt, float* __restrict__ attn)
{
    __shared__ __attribute__((aligned(16))) unsigned short ksh[64][72];
    __shared__ __attribute__((aligned(16))) unsigned short vsh[64][72];
    __shared__ __attribute__((aligned(16))) unsigned short psh[4][16][72];

    const int t = threadIdx.x, lane = t & 63, w = t >> 6;
    const int g = lane >> 4, lq = lane & 15;
    const int q0 = blockIdx.x * 64;
    const int bh = blockIdx.y;
    const int b  = bh >> 3, h = bh & 7;

    const unsigned short* Kb = Kw + (size_t)bh * S_ * HD_;
    const unsigned short* Vb = Vt + (size_t)bh * HD_ * S_;

    // Q B-fragments (held in registers for the whole kernel):
    // B[k=d][col=q]: lane holds Q[q=lq][d = kk*32 + g*8 + j]
    bf16x8 qf[2];
    #pragma unroll
    for (int kk = 0; kk < 2; ++kk)
        qf[kk] = *(const bf16x8*)(Qw + ((size_t)bh*S_ + q0 + w*16 + lq)*HD_ + kk*32 + g*8);

    f32x4 oacc[4];
    #pragma unroll
    for (int dn = 0; dn < 4; ++dn) oacc[dn] = (f32x4)0.f;
    float m = -1e30f, lsum = 0.f;

    for (int kt = 0; kt < 64; ++kt) {
        const int kv0 = kt * 64;
        __syncthreads();   // protect previous tile's LDS reads
        #pragma unroll
        for (int i = 0; i < 2; ++i) {
            int id = t + 256 * i; int row = id >> 3, c = id & 7;
            *(bf16x8*)&ksh[row][c*8] = *(const bf16x8*)(Kb + (size_t)(kv0 + row)*HD_ + c*8);
            *(bf16x8*)&vsh[row][c*8] = *(const bf16x8*)(Vb + (size_t)row*S_ + kv0 + c*8);
        }
        __syncthreads();

        // S^T tile: C[kv][q] = K_tile x Q^T  (4 kv-subtiles of 16)
        f32x4 st[4];
        #pragma unroll
        for (int n = 0; n < 4; ++n) {
            st[n] = (f32x4)0.f;
            #pragma unroll
            for (int kk = 0; kk < 2; ++kk) {
                bf16x8 kf = *(const bf16x8*)&ksh[n*16 + lq][kk*32 + g*8];
                st[n] = __builtin_amdgcn_mfma_f32_16x16x32_bf16(kf, qf[kk], st[n], 0, 0, 0);
            }
        }

        // online softmax for q-row lq: lane holds kv = n*16 + g*4 + r
        float mt = -1e30f;
        #pragma unroll
        for (int n = 0; n < 4; ++n)
            #pragma unroll
            for (int r = 0; r < 4; ++r) mt = fmaxf(mt, st[n][r]);
        mt = fmaxf(mt, __shfl_xor(mt, 16));
        mt = fmaxf(mt, __shfl_xor(mt, 32));
        float mnew = fmaxf(m, mt);
        float corr = exp2f(m - mnew);      // scores already in exp2 domain
        float p[16];
        float ts = 0.f;
        #pragma unroll
        for (int n = 0; n < 4; ++n)
            #pragma unroll
            for (int r = 0; r < 4; ++r) {
                float pv = exp2f(st[n][r] - mnew);
                p[n*4 + r] = pv; ts += pv;
            }
        ts += __shfl_xor(ts, 16);
        ts += __shfl_xor(ts, 32);
        lsum = lsum * corr + ts;
        m = mnew;

        // rescale O: O rows are q = g*4 + r; factor lives at lane (g*4+r)
        #pragma unroll
        for (int r = 0; r < 4; ++r) {
            float fr = __shfl(corr, g*4 + r);
            #pragma unroll
            for (int dn = 0; dn < 4; ++dn) oacc[dn][r] *= fr;
        }

        // write P row (bf16) to per-wave LDS: psh[w][q=lq][kv], kv = n*16+g*4..+3
        #pragma unroll
        for (int n = 0; n < 4; ++n) {
            unsigned int lo = f2bf(p[n*4+0]) | ((unsigned int)f2bf(p[n*4+1]) << 16);
            unsigned int hi = f2bf(p[n*4+2]) | ((unsigned int)f2bf(p[n*4+3]) << 16);
            *(uint2*)&psh[w][lq][n*16 + g*4] = make_uint2(lo, hi);
        }

        // PV: O[q][d] += P[16q x 32kv] * V[32kv x 16d]; B from V^T rows (contig)
        #pragma unroll
        for (int kk = 0; kk < 2; ++kk) {
            bf16x8 pf = *(const bf16x8*)&psh[w][lq][kk*32 + g*8];
            #pragma unroll
            for (int dn = 0; dn < 4; ++dn) {
                bf16x8 vf = *(const bf16x8*)&vsh[dn*16 + lq][kk*32 + g*8];
                oacc[dn] = __builtin_amdgcn_mfma_f32_16x16x32_bf16(pf, vf, oacc[dn], 0, 0, 0);
            }
        }
    }

    // epilogue: normalize and store fp32 [B][S][D] slice for this head
    #pragma unroll
    for (int r = 0; r < 4; ++r) {
        float ls  = __shfl(lsum, g*4 + r);
        float inv = 1.0f / ls;
        int srow = q0 + w*16 + g*4 + r;
        #pragma unroll
        for (int dn = 0; dn < 4; ++dn)
            attn[((size_t)b * S_ + srow) * D_ + h * HD_ + dn*16 + lq] = oacc[dn][r] * inv;
    }
}

// ---------------------------------------------------------------------------
// Kernel 3: residual + LayerNorm. One wave per row of 512. grid B*S/4, block 256
// ---------------------------------------------------------------------------
__global__ __launch_bounds__(256) void ln_kernel(
    const float* __restrict__ attn, const float* __restrict__ yy,
    const float* __restrict__ gamma, const float* __restrict__ beta,
    float* __restrict__ out)
{
    const int t = threadIdx.x, lane = t & 63, w = t >> 6;
    const size_t row = (size_t)blockIdx.x * 4 + w;
    const float* ar = attn + row * D_;
    const float* yr = yy + row * D_;

    float v[8];
    #pragma unroll
    for (int i = 0; i < 2; ++i) {
        float4 a  = *(const float4*)(ar + lane*8 + i*4);
        float4 yv = *(const float4*)(yr + lane*8 + i*4);
        v[i*4+0] = a.x + yv.x; v[i*4+1] = a.y + yv.y;
        v[i*4+2] = a.z + yv.z; v[i*4+3] = a.w + yv.w;
    }
    float s = 0.f;
    #pragma unroll
    for (int j = 0; j < 8; ++j) s += v[j];
    #pragma unroll
    for (int o = 32; o >= 1; o >>= 1) s += __shfl_xor(s, o);
    float mu = s * (1.f / 512.f);
    float qs = 0.f;
    #pragma unroll
    for (int j = 0; j < 8; ++j) { float d = v[j] - mu; qs += d * d; }
    #pragma unroll
    for (int o = 32; o >= 1; o >>= 1) qs += __shfl_xor(qs, o);
    float rstd = rsqrtf(qs * (1.f / 512.f) + 1e-5f);

    #pragma unroll
    for (int i = 0; i < 2; ++i) {
        float4 gm = *(const float4*)(gamma + lane*8 + i*4);
        float4 bt = *(const float4*)(beta  + lane*8 + i*4);
        float4 o4;
        o4.x = (v[i*4+0] - mu) * rstd * gm.x + bt.x;
        o4.y = (v[i*4+1] - mu) * rstd * gm.y + bt.y;
        o4.z = (v[i*4+2] - mu) * rstd * gm.z + bt.z;
        o4.w = (v[i*4+3] - mu) * rstd * gm.w + bt.w;
        *(float4*)(out + row * D_ + lane*8 + i*4) = o4;
    }
}

extern "C" void kernel_launch(void* const* d_in, const int* in_sizes, int n_in,
                              void* d_out, int out_size, void* d_ws, size_t ws_size,
                              hipStream_t stream) {
    const float* x     = (const float*)d_in[0];
    const float* y     = (const float*)d_in[1];
    const float* Wk    = (const float*)d_in[2];
    const float* bk    = (const float*)d_in[3];
    const float* Wq    = (const float*)d_in[4];
    const float* bq    = (const float*)d_in[5];
    const float* Wv    = (const float*)d_in[6];
    const float* bv    = (const float*)d_in[7];
    const float* gamma = (const float*)d_in[8];
    const float* beta  = (const float*)d_in[9];

    const size_t NTOK = (size_t)B_ * H_ * S_ * HD_;     // 4M elems per tensor
    unsigned short* Qw = (unsigned short*)d_ws;
    unsigned short* Kw = Qw + NTOK;
    unsigned short* Vt = Kw + NTOK;
    float* attnbuf = (float*)(Vt + NTOK);               // 16 MB fp32

    dim3 grid(S_ / 64, B_ * H_);
    proj_kernel<<<grid, 256, 0, stream>>>(x, y, Wk, bk, Wq, bq, Wv, bv, Qw, Kw, Vt);
    attn_kernel<<<grid, 256, 0, stream>>>(Qw, Kw, Vt, attnbuf);
    ln_kernel<<<(B_ * S_) / 4, 256, 0, stream>>>(attnbuf, y, gamma, beta, (float*)d_out);
}

// Round 7
// 173.315 us; speedup vs baseline: 1.1683x; 1.1683x over previous
//
#include <hip/hip_runtime.h>
#include <hip/hip_bf16.h>

#define B_  2
#define S_  4096
#define H_  8
#define HD_ 64
#define D_  512

using bf16x8 = __attribute__((ext_vector_type(8))) short;  // 8 bf16 in 4 VGPRs
using f32x4  = __attribute__((ext_vector_type(4))) float;

__device__ __forceinline__ unsigned short f2bf(float f) {
    unsigned int u = __float_as_uint(f);
    u += 0x7FFFu + ((u >> 16) & 1u);   // RNE
    return (unsigned short)(u >> 16);
}

// packed f32x2 -> bf16x2 via v_cvt_pk_bf16_f32 (no builtin on gfx950; T12 recipe)
__device__ __forceinline__ unsigned int pkbf(float a, float b) {
    unsigned int r;
    asm("v_cvt_pk_bf16_f32 %0, %1, %2" : "=v"(r) : "v"(a), "v"(b));
    return r;
}

// ---------------------------------------------------------------------------
// Kernel 1: per-head QKV projection.  grid (S/64, B*H), block 256 (4 waves)
// K[bh][s][e], Q[bh][s][e] (pre-scaled by 0.125*log2e), Vt[bh][e][s]  (bf16)
// ---------------------------------------------------------------------------
__global__ __launch_bounds__(256) void proj_kernel(
    const float* __restrict__ x,  const float* __restrict__ yy,
    const float* __restrict__ Wk, const float* __restrict__ bk,
    const float* __restrict__ Wq, const float* __restrict__ bq,
    const float* __restrict__ Wv, const float* __restrict__ bv,
    unsigned short* __restrict__ Qw, unsigned short* __restrict__ Kw,
    unsigned short* __restrict__ Vt)
{
    __shared__ __attribute__((aligned(16))) unsigned short xs[64][72];
    __shared__ __attribute__((aligned(16))) unsigned short ys[64][72];
    __shared__ __attribute__((aligned(16))) unsigned short wtk[64][72];
    __shared__ __attribute__((aligned(16))) unsigned short wtq[64][72];
    __shared__ __attribute__((aligned(16))) unsigned short wtv[64][72];
    __shared__ __attribute__((aligned(16))) unsigned short vtl[64][72];

    const int t  = threadIdx.x;
    const int s0 = blockIdx.x * 64;
    const int bh = blockIdx.y;
    const int b  = bh >> 3, h = bh & 7;

    #pragma unroll
    for (int i = 0; i < 4; ++i) {
        int id = t + 256 * i;
        int row = id >> 4, c4 = id & 15;
        size_t ga = ((size_t)(b * S_ + s0 + row)) * D_ + h * HD_ + c4 * 4;
        float4 xv = *(const float4*)(x + ga);
        float4 yv = *(const float4*)(yy + ga);
        unsigned int xl = f2bf(xv.x) | ((unsigned int)f2bf(xv.y) << 16);
        unsigned int xh = f2bf(xv.z) | ((unsigned int)f2bf(xv.w) << 16);
        unsigned int yl = f2bf(yv.x) | ((unsigned int)f2bf(yv.y) << 16);
        unsigned int yh = f2bf(yv.z) | ((unsigned int)f2bf(yv.w) << 16);
        *(uint2*)&xs[row][c4 * 4] = make_uint2(xl, xh);
        *(uint2*)&ys[row][c4 * 4] = make_uint2(yl, yh);
    }
    #pragma unroll
    for (int i = 0; i < 4; ++i) {
        int id = t + 256 * i;
        int dd = id >> 4, e4 = id & 15;
        size_t wa = (size_t)(h * HD_ + dd) * HD_ + e4 * 4;
        float4 wk4 = *(const float4*)(Wk + wa);
        float4 wq4 = *(const float4*)(Wq + wa);
        float4 wv4 = *(const float4*)(Wv + wa);
        wtk[e4*4+0][dd] = f2bf(wk4.x); wtk[e4*4+1][dd] = f2bf(wk4.y);
        wtk[e4*4+2][dd] = f2bf(wk4.z); wtk[e4*4+3][dd] = f2bf(wk4.w);
        wtq[e4*4+0][dd] = f2bf(wq4.x); wtq[e4*4+1][dd] = f2bf(wq4.y);
        wtq[e4*4+2][dd] = f2bf(wq4.z); wtq[e4*4+3][dd] = f2bf(wq4.w);
        wtv[e4*4+0][dd] = f2bf(wv4.x); wtv[e4*4+1][dd] = f2bf(wv4.y);
        wtv[e4*4+2][dd] = f2bf(wv4.z); wtv[e4*4+3][dd] = f2bf(wv4.w);
    }
    __syncthreads();

    const int lane = t & 63, w = t >> 6;
    const int g = lane >> 4, lq = lane & 15;

    bf16x8 ax[2], ay[2];
    #pragma unroll
    for (int kk = 0; kk < 2; ++kk) {
        ax[kk] = *(const bf16x8*)&xs[w*16 + lq][kk*32 + g*8];
        ay[kk] = *(const bf16x8*)&ys[w*16 + lq][kk*32 + g*8];
    }

    f32x4 ak[4], aq[4], av[4];
    #pragma unroll
    for (int n = 0; n < 4; ++n) { ak[n] = (f32x4)0.f; aq[n] = (f32x4)0.f; av[n] = (f32x4)0.f; }

    #pragma unroll
    for (int n = 0; n < 4; ++n) {
        #pragma unroll
        for (int kk = 0; kk < 2; ++kk) {
            bf16x8 bk_ = *(const bf16x8*)&wtk[n*16 + lq][kk*32 + g*8];
            ak[n] = __builtin_amdgcn_mfma_f32_16x16x32_bf16(ax[kk], bk_, ak[n], 0, 0, 0);
            bf16x8 bq_ = *(const bf16x8*)&wtq[n*16 + lq][kk*32 + g*8];
            aq[n] = __builtin_amdgcn_mfma_f32_16x16x32_bf16(ay[kk], bq_, aq[n], 0, 0, 0);
            bf16x8 bv_ = *(const bf16x8*)&wtv[n*16 + lq][kk*32 + g*8];
            av[n] = __builtin_amdgcn_mfma_f32_16x16x32_bf16(ax[kk], bv_, av[n], 0, 0, 0);
        }
    }

    const float cscale = 0.125f * 1.44269504088896340736f;
    #pragma unroll
    for (int n = 0; n < 4; ++n) {
        int e = n*16 + lq;
        float bkv = bk[h*HD_ + e], bqv = bq[h*HD_ + e], bvv = bv[h*HD_ + e];
        #pragma unroll
        for (int r = 0; r < 4; ++r) {
            int srow = w*16 + g*4 + r;
            size_t o = ((size_t)bh * S_ + s0 + srow) * HD_ + e;
            Kw[o] = f2bf(ak[n][r] + bkv);
            Qw[o] = f2bf((aq[n][r] + bqv) * cscale);
            vtl[e][srow] = f2bf(av[n][r] + bvv);
        }
    }
    __syncthreads();
    #pragma unroll
    for (int i = 0; i < 2; ++i) {
        int id = t + 256 * i;
        int e = id >> 3, c = id & 7;
        bf16x8 v = *(const bf16x8*)&vtl[e][c*8];
        *(bf16x8*)(Vt + ((size_t)bh * HD_ + e) * S_ + s0 + c*8) = v;
    }
}

// ---------------------------------------------------------------------------
// Kernel 2: flash attention. grid (S/64, B*H), block 256 (4 waves x 16 q-rows)
// Swapped QK^T; defer-max softmax; row-sum via MFMA ones-column;
// prefetch-to-reg K/V staging.
// ---------------------------------------------------------------------------
__global__ __launch_bounds__(256) void attn_kernel(
    const unsigned short* __restrict__ Qw, const unsigned short* __restrict__ Kw,
    const unsigned short* __restrict__ Vt, float* __restrict__ attn)
{
    __shared__ __attribute__((aligned(16))) unsigned short ksh[64][72];
    __shared__ __attribute__((aligned(16))) unsigned short vsh[64][72];
    __shared__ __attribute__((aligned(16))) unsigned short psh[4][16][72];

    const int t = threadIdx.x, lane = t & 63, w = t >> 6;
    const int g = lane >> 4, lq = lane & 15;
    const int q0 = blockIdx.x * 64;
    const int bh = blockIdx.y;
    const int b  = bh >> 3, h = bh & 7;

    const unsigned short* Kb = Kw + (size_t)bh * S_ * HD_;
    const unsigned short* Vb = Vt + (size_t)bh * HD_ * S_;

    bf16x8 qf[2];
    #pragma unroll
    for (int kk = 0; kk < 2; ++kk)
        qf[kk] = *(const bf16x8*)(Qw + ((size_t)bh*S_ + q0 + w*16 + lq)*HD_ + kk*32 + g*8);

    // all-ones B fragment: every output column of mfma(P, ones) = row-sum of P
    bf16x8 ones;
    #pragma unroll
    for (int j = 0; j < 8; ++j) ones[j] = (short)0x3F80;

    f32x4 oacc[4];
    #pragma unroll
    for (int dn = 0; dn < 4; ++dn) oacc[dn] = (f32x4)0.f;
    f32x4 sacc = (f32x4)0.f;
    float m = -1e30f;

    // prefetch registers for K/V staging (each thread stages 2x16B per tensor)
    const int r0 = t >> 3, c0 = (t & 7) * 8;
    bf16x8 kr0 = *(const bf16x8*)(Kb + (size_t)r0 * HD_ + c0);
    bf16x8 kr1 = *(const bf16x8*)(Kb + (size_t)(r0 + 32) * HD_ + c0);
    bf16x8 vr0 = *(const bf16x8*)(Vb + (size_t)r0 * S_ + c0);
    bf16x8 vr1 = *(const bf16x8*)(Vb + (size_t)(r0 + 32) * S_ + c0);

    for (int kt = 0; kt < 64; ++kt) {
        __syncthreads();   // prior tile's LDS reads complete
        *(bf16x8*)&ksh[r0][c0]      = kr0;
        *(bf16x8*)&ksh[r0 + 32][c0] = kr1;
        *(bf16x8*)&vsh[r0][c0]      = vr0;
        *(bf16x8*)&vsh[r0 + 32][c0] = vr1;
        __syncthreads();

        if (kt < 63) {   // issue next tile's loads; consumed at next ds_write
            const int kn = (kt + 1) * 64;
            kr0 = *(const bf16x8*)(Kb + (size_t)(kn + r0) * HD_ + c0);
            kr1 = *(const bf16x8*)(Kb + (size_t)(kn + r0 + 32) * HD_ + c0);
            vr0 = *(const bf16x8*)(Vb + (size_t)r0 * S_ + kn + c0);
            vr1 = *(const bf16x8*)(Vb + (size_t)(r0 + 32) * S_ + kn + c0);
        }

        // S^T tile: C[kv][q] = K_tile x Q^T
        f32x4 st[4];
        #pragma unroll
        for (int n = 0; n < 4; ++n) {
            st[n] = (f32x4)0.f;
            #pragma unroll
            for (int kk = 0; kk < 2; ++kk) {
                bf16x8 kf = *(const bf16x8*)&ksh[n*16 + lq][kk*32 + g*8];
                st[n] = __builtin_amdgcn_mfma_f32_16x16x32_bf16(kf, qf[kk], st[n], 0, 0, 0);
            }
        }

        // tile max for q-row lq (lane holds kv = n*16 + g*4 + r)
        float h0 = fmaxf(fmaxf(st[0][0], st[0][1]), fmaxf(st[0][2], st[0][3]));
        float h1 = fmaxf(fmaxf(st[1][0], st[1][1]), fmaxf(st[1][2], st[1][3]));
        float h2 = fmaxf(fmaxf(st[2][0], st[2][1]), fmaxf(st[2][2], st[2][3]));
        float h3 = fmaxf(fmaxf(st[3][0], st[3][1]), fmaxf(st[3][2], st[3][3]));
        float mt = fmaxf(fmaxf(h0, h1), fmaxf(h2, h3));
        mt = fmaxf(mt, __shfl_xor(mt, 16));
        mt = fmaxf(mt, __shfl_xor(mt, 32));

        // defer-max: only rescale when tile max exceeds running max by >8
        // (exp2 domain: P values stay bounded by 2^8, safe in bf16/f32)
        if (!__all(mt <= m + 8.0f)) {
            float mnew = fmaxf(m, mt);
            float corr = exp2f(m - mnew);
            #pragma unroll
            for (int r = 0; r < 4; ++r) {
                float fr = __shfl(corr, g*4 + r);
                #pragma unroll
                for (int dn = 0; dn < 4; ++dn) oacc[dn][r] *= fr;
                sacc[r] *= fr;
            }
            m = mnew;
        }

        // P = exp2(st - m), pack to bf16 via v_cvt_pk
        float p[16];
        #pragma unroll
        for (int n = 0; n < 4; ++n)
            #pragma unroll
            for (int r = 0; r < 4; ++r)
                p[n*4 + r] = exp2f(st[n][r] - m);
        #pragma unroll
        for (int n = 0; n < 4; ++n)
            *(uint2*)&psh[w][lq][n*16 + g*4] =
                make_uint2(pkbf(p[n*4+0], p[n*4+1]), pkbf(p[n*4+2], p[n*4+3]));

        // PV + row-sum: O += P*V^T ; sacc += P*ones (sum on MFMA pipe)
        #pragma unroll
        for (int kk = 0; kk < 2; ++kk) {
            bf16x8 pf = *(const bf16x8*)&psh[w][lq][kk*32 + g*8];
            sacc = __builtin_amdgcn_mfma_f32_16x16x32_bf16(pf, ones, sacc, 0, 0, 0);
            #pragma unroll
            for (int dn = 0; dn < 4; ++dn) {
                bf16x8 vf = *(const bf16x8*)&vsh[dn*16 + lq][kk*32 + g*8];
                oacc[dn] = __builtin_amdgcn_mfma_f32_16x16x32_bf16(pf, vf, oacc[dn], 0, 0, 0);
            }
        }
    }

    // epilogue: sacc[r] is the row-sum for q-row g*4+r (replicated over lq)
    #pragma unroll
    for (int r = 0; r < 4; ++r) {
        float inv = 1.0f / sacc[r];
        int srow = q0 + w*16 + g*4 + r;
        #pragma unroll
        for (int dn = 0; dn < 4; ++dn)
            attn[((size_t)b * S_ + srow) * D_ + h * HD_ + dn*16 + lq] = oacc[dn][r] * inv;
    }
}

// ---------------------------------------------------------------------------
// Kernel 3: residual + LayerNorm. One wave per row of 512. grid B*S/4, block 256
// ---------------------------------------------------------------------------
__global__ __launch_bounds__(256) void ln_kernel(
    const float* __restrict__ attn, const float* __restrict__ yy,
    const float* __restrict__ gamma, const float* __restrict__ beta,
    float* __restrict__ out)
{
    const int t = threadIdx.x, lane = t & 63, w = t >> 6;
    const size_t row = (size_t)blockIdx.x * 4 + w;
    const float* ar = attn + row * D_;
    const float* yr = yy + row * D_;

    float v[8];
    #pragma unroll
    for (int i = 0; i < 2; ++i) {
        float4 a  = *(const float4*)(ar + lane*8 + i*4);
        float4 yv = *(const float4*)(yr + lane*8 + i*4);
        v[i*4+0] = a.x + yv.x; v[i*4+1] = a.y + yv.y;
        v[i*4+2] = a.z + yv.z; v[i*4+3] = a.w + yv.w;
    }
    float s = 0.f;
    #pragma unroll
    for (int j = 0; j < 8; ++j) s += v[j];
    #pragma unroll
    for (int o = 32; o >= 1; o >>= 1) s += __shfl_xor(s, o);
    float mu = s * (1.f / 512.f);
    float qs = 0.f;
    #pragma unroll
    for (int j = 0; j < 8; ++j) { float d = v[j] - mu; qs += d * d; }
    #pragma unroll
    for (int o = 32; o >= 1; o >>= 1) qs += __shfl_xor(qs, o);
    float rstd = rsqrtf(qs * (1.f / 512.f) + 1e-5f);

    #pragma unroll
    for (int i = 0; i < 2; ++i) {
        float4 gm = *(const float4*)(gamma + lane*8 + i*4);
        float4 bt = *(const float4*)(beta  + lane*8 + i*4);
        float4 o4;
        o4.x = (v[i*4+0] - mu) * rstd * gm.x + bt.x;
        o4.y = (v[i*4+1] - mu) * rstd * gm.y + bt.y;
        o4.z = (v[i*4+2] - mu) * rstd * gm.z + bt.z;
        o4.w = (v[i*4+3] - mu) * rstd * gm.w + bt.w;
        *(float4*)(out + row * D_ + lane*8 + i*4) = o4;
    }
}

extern "C" void kernel_launch(void* const* d_in, const int* in_sizes, int n_in,
                              void* d_out, int out_size, void* d_ws, size_t ws_size,
                              hipStream_t stream) {
    const float* x     = (const float*)d_in[0];
    const float* y     = (const float*)d_in[1];
    const float* Wk    = (const float*)d_in[2];
    const float* bk    = (const float*)d_in[3];
    const float* Wq    = (const float*)d_in[4];
    const float* bq    = (const float*)d_in[5];
    const float* Wv    = (const float*)d_in[6];
    const float* bv    = (const float*)d_in[7];
    const float* gamma = (const float*)d_in[8];
    const float* beta  = (const float*)d_in[9];

    const size_t NTOK = (size_t)B_ * H_ * S_ * HD_;
    unsigned short* Qw = (unsigned short*)d_ws;
    unsigned short* Kw = Qw + NTOK;
    unsigned short* Vt = Kw + NTOK;
    float* attnbuf = (float*)(Vt + NTOK);

    dim3 grid(S_ / 64, B_ * H_);
    proj_kernel<<<grid, 256, 0, stream>>>(x, y, Wk, bk, Wq, bq, Wv, bv, Qw, Kw, Vt);
    attn_kernel<<<grid, 256, 0, stream>>>(Qw, Kw, Vt, attnbuf);
    ln_kernel<<<(B_ * S_) / 4, 256, 0, stream>>>(attnbuf, y, gamma, beta, (float*)d_out);
}

// Round 8
// 160.090 us; speedup vs baseline: 1.2648x; 1.0826x over previous
//
#include <hip/hip_runtime.h>
#include <hip/hip_bf16.h>

#define B_  2
#define S_  4096
#define H_  8
#define HD_ 64
#define D_  512

using bf16x8 = __attribute__((ext_vector_type(8))) short;   // 8 bf16 in 4 VGPRs
using f32x4  = __attribute__((ext_vector_type(4))) float;
using f32x16 = __attribute__((ext_vector_type(16))) float;
using u32x4  = __attribute__((ext_vector_type(4))) unsigned int;

__device__ __forceinline__ unsigned short f2bf(float f) {
    unsigned int u = __float_as_uint(f);
    u += 0x7FFFu + ((u >> 16) & 1u);   // RNE
    return (unsigned short)(u >> 16);
}

// packed f32x2 -> bf16x2 via v_cvt_pk_bf16_f32 (no builtin on gfx950; T12 recipe)
__device__ __forceinline__ unsigned int pkbf(float a, float b) {
    unsigned int r;
    asm("v_cvt_pk_bf16_f32 %0, %1, %2" : "=v"(r) : "v"(a), "v"(b));
    return r;
}

// ---------------------------------------------------------------------------
// Kernel 1: per-head QKV projection.  grid (S/64, B*H), block 256 (4 waves)
// K[bh][s][e], Q[bh][s][e] (pre-scaled by 0.125*log2e), Vt[bh][e][s]  (bf16)
// ---------------------------------------------------------------------------
__global__ __launch_bounds__(256) void proj_kernel(
    const float* __restrict__ x,  const float* __restrict__ yy,
    const float* __restrict__ Wk, const float* __restrict__ bk,
    const float* __restrict__ Wq, const float* __restrict__ bq,
    const float* __restrict__ Wv, const float* __restrict__ bv,
    unsigned short* __restrict__ Qw, unsigned short* __restrict__ Kw,
    unsigned short* __restrict__ Vt)
{
    __shared__ __attribute__((aligned(16))) unsigned short xs[64][72];
    __shared__ __attribute__((aligned(16))) unsigned short ys[64][72];
    __shared__ __attribute__((aligned(16))) unsigned short wtk[64][72];
    __shared__ __attribute__((aligned(16))) unsigned short wtq[64][72];
    __shared__ __attribute__((aligned(16))) unsigned short wtv[64][72];
    __shared__ __attribute__((aligned(16))) unsigned short vtl[64][72];

    const int t  = threadIdx.x;
    const int s0 = blockIdx.x * 64;
    const int bh = blockIdx.y;
    const int b  = bh >> 3, h = bh & 7;

    #pragma unroll
    for (int i = 0; i < 4; ++i) {
        int id = t + 256 * i;
        int row = id >> 4, c4 = id & 15;
        size_t ga = ((size_t)(b * S_ + s0 + row)) * D_ + h * HD_ + c4 * 4;
        float4 xv = *(const float4*)(x + ga);
        float4 yv = *(const float4*)(yy + ga);
        unsigned int xl = f2bf(xv.x) | ((unsigned int)f2bf(xv.y) << 16);
        unsigned int xh = f2bf(xv.z) | ((unsigned int)f2bf(xv.w) << 16);
        unsigned int yl = f2bf(yv.x) | ((unsigned int)f2bf(yv.y) << 16);
        unsigned int yh = f2bf(yv.z) | ((unsigned int)f2bf(yv.w) << 16);
        *(uint2*)&xs[row][c4 * 4] = make_uint2(xl, xh);
        *(uint2*)&ys[row][c4 * 4] = make_uint2(yl, yh);
    }
    #pragma unroll
    for (int i = 0; i < 4; ++i) {
        int id = t + 256 * i;
        int dd = id >> 4, e4 = id & 15;
        size_t wa = (size_t)(h * HD_ + dd) * HD_ + e4 * 4;
        float4 wk4 = *(const float4*)(Wk + wa);
        float4 wq4 = *(const float4*)(Wq + wa);
        float4 wv4 = *(const float4*)(Wv + wa);
        wtk[e4*4+0][dd] = f2bf(wk4.x); wtk[e4*4+1][dd] = f2bf(wk4.y);
        wtk[e4*4+2][dd] = f2bf(wk4.z); wtk[e4*4+3][dd] = f2bf(wk4.w);
        wtq[e4*4+0][dd] = f2bf(wq4.x); wtq[e4*4+1][dd] = f2bf(wq4.y);
        wtq[e4*4+2][dd] = f2bf(wq4.z); wtq[e4*4+3][dd] = f2bf(wq4.w);
        wtv[e4*4+0][dd] = f2bf(wv4.x); wtv[e4*4+1][dd] = f2bf(wv4.y);
        wtv[e4*4+2][dd] = f2bf(wv4.z); wtv[e4*4+3][dd] = f2bf(wv4.w);
    }
    __syncthreads();

    const int lane = t & 63, w = t >> 6;
    const int g = lane >> 4, lq = lane & 15;

    bf16x8 ax[2], ay[2];
    #pragma unroll
    for (int kk = 0; kk < 2; ++kk) {
        ax[kk] = *(const bf16x8*)&xs[w*16 + lq][kk*32 + g*8];
        ay[kk] = *(const bf16x8*)&ys[w*16 + lq][kk*32 + g*8];
    }

    f32x4 ak[4], aq[4], av[4];
    #pragma unroll
    for (int n = 0; n < 4; ++n) { ak[n] = (f32x4)0.f; aq[n] = (f32x4)0.f; av[n] = (f32x4)0.f; }

    #pragma unroll
    for (int n = 0; n < 4; ++n) {
        #pragma unroll
        for (int kk = 0; kk < 2; ++kk) {
            bf16x8 bk_ = *(const bf16x8*)&wtk[n*16 + lq][kk*32 + g*8];
            ak[n] = __builtin_amdgcn_mfma_f32_16x16x32_bf16(ax[kk], bk_, ak[n], 0, 0, 0);
            bf16x8 bq_ = *(const bf16x8*)&wtq[n*16 + lq][kk*32 + g*8];
            aq[n] = __builtin_amdgcn_mfma_f32_16x16x32_bf16(ay[kk], bq_, aq[n], 0, 0, 0);
            bf16x8 bv_ = *(const bf16x8*)&wtv[n*16 + lq][kk*32 + g*8];
            av[n] = __builtin_amdgcn_mfma_f32_16x16x32_bf16(ax[kk], bv_, av[n], 0, 0, 0);
        }
    }

    const float cscale = 0.125f * 1.44269504088896340736f;
    #pragma unroll
    for (int n = 0; n < 4; ++n) {
        int e = n*16 + lq;
        float bkv = bk[h*HD_ + e], bqv = bq[h*HD_ + e], bvv = bv[h*HD_ + e];
        #pragma unroll
        for (int r = 0; r < 4; ++r) {
            int srow = w*16 + g*4 + r;
            size_t o = ((size_t)bh * S_ + s0 + srow) * HD_ + e;
            Kw[o] = f2bf(ak[n][r] + bkv);
            Qw[o] = f2bf((aq[n][r] + bqv) * cscale);
            vtl[e][srow] = f2bf(av[n][r] + bvv);
        }
    }
    __syncthreads();
    #pragma unroll
    for (int i = 0; i < 2; ++i) {
        int id = t + 256 * i;
        int e = id >> 3, c = id & 7;
        bf16x8 v = *(const bf16x8*)&vtl[e][c*8];
        *(bf16x8*)(Vt + ((size_t)bh * HD_ + e) * S_ + s0 + c*8) = v;
    }
}

// ---------------------------------------------------------------------------
// Kernel 2: flash attention, 32x32 MFMA structure.
// grid (S/256, B*H), block 512 (8 waves x 32 q-rows each), KVBLK=64.
// Swapped QK^T: st = mfma(K, Q) -> C[kv][q], col=lane&31 = q: each lane owns
// a full P-row for ONE q. Softmax fully lane-local (+1 shfl for hi-half).
// P -> PV B-fragments in-register via cvt_pk + v_permlane32_swap (T12).
// K/V LDS tiles XOR-swizzled (T2): col ^ ((row&7)*8), [64][64] bf16.
// ---------------------------------------------------------------------------
__global__ __launch_bounds__(512, 2) void attn_kernel(
    const unsigned short* __restrict__ Qw, const unsigned short* __restrict__ Kw,
    const unsigned short* __restrict__ Vt, float* __restrict__ attn)
{
    __shared__ __attribute__((aligned(16))) unsigned short ksh[64][64];
    __shared__ __attribute__((aligned(16))) unsigned short vsh[64][64];

    const int t = threadIdx.x, lane = t & 63, w = t >> 6;   // 8 waves
    const int lx = lane & 31, hi = lane >> 5;
    const int q0 = blockIdx.x * 256;
    const int bh = blockIdx.y;
    const int b  = bh >> 3, h = bh & 7;

    const unsigned short* Kb = Kw + (size_t)bh * S_ * HD_;
    const unsigned short* Vb = Vt + (size_t)bh * HD_ * S_;

    // Q B-fragments: B[k = kq*16 + hi*8 + j][col=q=lx], held all kernel
    bf16x8 qf[4];
    #pragma unroll
    for (int kq = 0; kq < 4; ++kq)
        qf[kq] = *(const bf16x8*)(Qw + ((size_t)bh*S_ + q0 + w*32 + lx)*HD_ + kq*16 + hi*8);

    bf16x8 ones;
    #pragma unroll
    for (int j = 0; j < 8; ++j) ones[j] = (short)0x3F80;

    f32x16 oaccT[2];           // O^T[d][q]: d-blocks of 32
    oaccT[0] = (f32x16)0.f; oaccT[1] = (f32x16)0.f;
    f32x16 sacc = (f32x16)0.f; // all rows hold row-sum(P) for q=lx
    float m = -1e30f;

    // staging: 512 threads, 1x16B chunk per tensor each
    const int srow = t >> 3;               // 0..63
    const int scol = (t & 7) * 8;          // 0..56
    const int swcol = scol ^ ((srow & 7) * 8);   // T2 XOR swizzle
    bf16x8 kr = *(const bf16x8*)(Kb + (size_t)srow * HD_ + scol);
    bf16x8 vr = *(const bf16x8*)(Vb + (size_t)srow * S_ + scol);

    for (int kt = 0; kt < 64; ++kt) {
        __syncthreads();   // prior tile's LDS reads complete
        *(bf16x8*)&ksh[srow][swcol] = kr;
        *(bf16x8*)&vsh[srow][swcol] = vr;
        __syncthreads();

        if (kt < 63) {     // prefetch next tile; consumed at next ds_write
            const int kn = (kt + 1) * 64;
            kr = *(const bf16x8*)(Kb + (size_t)(kn + srow) * HD_ + scol);
            vr = *(const bf16x8*)(Vb + (size_t)srow * S_ + kn + scol);
        }

        // QK^T: st[blk] = C[kv = blk*32 + rows][q = lx]
        f32x16 st[2];
        #pragma unroll
        for (int blk = 0; blk < 2; ++blk) {
            st[blk] = (f32x16)0.f;
            const int krow = blk*32 + lx;
            #pragma unroll
            for (int kq = 0; kq < 4; ++kq) {
                bf16x8 kf = *(const bf16x8*)&ksh[krow][(kq*16 + hi*8) ^ ((krow & 7)*8)];
                st[blk] = __builtin_amdgcn_mfma_f32_32x32x16_bf16(kf, qf[kq], st[blk], 0, 0, 0);
            }
        }

        // lane-local tile max over 32 values + hi-half combine
        float mt = -1e30f;
        #pragma unroll
        for (int r = 0; r < 16; ++r) mt = fmaxf(mt, fmaxf(st[0][r], st[1][r]));
        mt = fmaxf(mt, __shfl_xor(mt, 32));

        // defer-max (exp2 domain, P bounded by 2^8)
        if (!__all(mt <= m + 8.0f)) {
            float mnew = fmaxf(m, mt);
            float corr = exp2f(m - mnew);
            #pragma unroll
            for (int r = 0; r < 16; ++r) {
                oaccT[0][r] *= corr; oaccT[1][r] *= corr; sacc[r] *= corr;
            }
            m = mnew;
        }

        // P = exp2(st - m)
        float p0[16], p1[16];
        #pragma unroll
        for (int r = 0; r < 16; ++r) {
            p0[r] = exp2f(st[0][r] - m);
            p1[r] = exp2f(st[1][r] - m);
        }

        // PV: build B[k=kv][col=q] fragments in-register per ks (16 kv each).
        // Owned pair (blk,u,cp): kv = 32blk + 8u + 4hi + 2cp -> word for
        // (ks = 2blk + (u>>1), hi_t = u&1, jw = 2hi + cp).  permlane32_swap
        // of (hi_t=0, hi_t=1) words yields B[ks][cp] and B[ks][2+cp].
        #pragma unroll
        for (int ks = 0; ks < 4; ++ks) {
            const int u0 = (ks & 1) * 2;
            unsigned int w0, w1, w2, w3;
            if (ks < 2) {
                w0 = pkbf(p0[4*u0+0],     p0[4*u0+1]);
                w2 = pkbf(p0[4*(u0+1)+0], p0[4*(u0+1)+1]);
                w1 = pkbf(p0[4*u0+2],     p0[4*u0+3]);
                w3 = pkbf(p0[4*(u0+1)+2], p0[4*(u0+1)+3]);
            } else {
                w0 = pkbf(p1[4*u0+0],     p1[4*u0+1]);
                w2 = pkbf(p1[4*(u0+1)+0], p1[4*(u0+1)+1]);
                w1 = pkbf(p1[4*u0+2],     p1[4*u0+3]);
                w3 = pkbf(p1[4*(u0+1)+2], p1[4*(u0+1)+3]);
            }
            asm("v_permlane32_swap_b32 %0, %1" : "+v"(w0), "+v"(w2));
            asm("v_permlane32_swap_b32 %0, %1" : "+v"(w1), "+v"(w3));
            u32x4 pw; pw.x = w0; pw.y = w1; pw.z = w2; pw.w = w3;
            bf16x8 pB = __builtin_bit_cast(bf16x8, pw);

            sacc = __builtin_amdgcn_mfma_f32_32x32x16_bf16(ones, pB, sacc, 0, 0, 0);
            #pragma unroll
            for (int d0 = 0; d0 < 2; ++d0) {
                const int vrow = d0*32 + lx;
                bf16x8 vf = *(const bf16x8*)&vsh[vrow][(ks*16 + hi*8) ^ ((vrow & 7)*8)];
                oaccT[d0] = __builtin_amdgcn_mfma_f32_32x32x16_bf16(vf, pB, oaccT[d0], 0, 0, 0);
            }
        }
    }

    // epilogue: O^T[d][q=lx] / rowsum; d = d0*32 + 8u + 4hi + (reg&3)
    float inv = 1.0f / sacc[0];
    const int qrow = q0 + w*32 + lx;
    float* orow = attn + ((size_t)b * S_ + qrow) * D_ + h * HD_;
    #pragma unroll
    for (int d0 = 0; d0 < 2; ++d0)
        #pragma unroll
        for (int u = 0; u < 4; ++u) {
            float4 o4;
            o4.x = oaccT[d0][4*u+0] * inv;
            o4.y = oaccT[d0][4*u+1] * inv;
            o4.z = oaccT[d0][4*u+2] * inv;
            o4.w = oaccT[d0][4*u+3] * inv;
            *(float4*)(orow + d0*32 + 8*u + 4*hi) = o4;
        }
}

// ---------------------------------------------------------------------------
// Kernel 3: residual + LayerNorm. One wave per row of 512. grid B*S/4, block 256
// ---------------------------------------------------------------------------
__global__ __launch_bounds__(256) void ln_kernel(
    const float* __restrict__ attn, const float* __restrict__ yy,
    const float* __restrict__ gamma, const float* __restrict__ beta,
    float* __restrict__ out)
{
    const int t = threadIdx.x, lane = t & 63, w = t >> 6;
    const size_t row = (size_t)blockIdx.x * 4 + w;
    const float* ar = attn + row * D_;
    const float* yr = yy + row * D_;

    float v[8];
    #pragma unroll
    for (int i = 0; i < 2; ++i) {
        float4 a  = *(const float4*)(ar + lane*8 + i*4);
        float4 yv = *(const float4*)(yr + lane*8 + i*4);
        v[i*4+0] = a.x + yv.x; v[i*4+1] = a.y + yv.y;
        v[i*4+2] = a.z + yv.z; v[i*4+3] = a.w + yv.w;
    }
    float s = 0.f;
    #pragma unroll
    for (int j = 0; j < 8; ++j) s += v[j];
    #pragma unroll
    for (int o = 32; o >= 1; o >>= 1) s += __shfl_xor(s, o);
    float mu = s * (1.f / 512.f);
    float qs = 0.f;
    #pragma unroll
    for (int j = 0; j < 8; ++j) { float d = v[j] - mu; qs += d * d; }
    #pragma unroll
    for (int o = 32; o >= 1; o >>= 1) qs += __shfl_xor(qs, o);
    float rstd = rsqrtf(qs * (1.f / 512.f) + 1e-5f);

    #pragma unroll
    for (int i = 0; i < 2; ++i) {
        float4 gm = *(const float4*)(gamma + lane*8 + i*4);
        float4 bt = *(const float4*)(beta  + lane*8 + i*4);
        float4 o4;
        o4.x = (v[i*4+0] - mu) * rstd * gm.x + bt.x;
        o4.y = (v[i*4+1] - mu) * rstd * gm.y + bt.y;
        o4.z = (v[i*4+2] - mu) * rstd * gm.z + bt.z;
        o4.w = (v[i*4+3] - mu) * rstd * gm.w + bt.w;
        *(float4*)(out + row * D_ + lane*8 + i*4) = o4;
    }
}

extern "C" void kernel_launch(void* const* d_in, const int* in_sizes, int n_in,
                              void* d_out, int out_size, void* d_ws, size_t ws_size,
                              hipStream_t stream) {
    const float* x     = (const float*)d_in[0];
    const float* y     = (const float*)d_in[1];
    const float* Wk    = (const float*)d_in[2];
    const float* bk    = (const float*)d_in[3];
    const float* Wq    = (const float*)d_in[4];
    const float* bq    = (const float*)d_in[5];
    const float* Wv    = (const float*)d_in[6];
    const float* bv    = (const float*)d_in[7];
    const float* gamma = (const float*)d_in[8];
    const float* beta  = (const float*)d_in[9];

    const size_t NTOK = (size_t)B_ * H_ * S_ * HD_;
    unsigned short* Qw = (unsigned short*)d_ws;
    unsigned short* Kw = Qw + NTOK;
    unsigned short* Vt = Kw + NTOK;
    float* attnbuf = (float*)(Vt + NTOK);

    dim3 pgrid(S_ / 64, B_ * H_);
    proj_kernel<<<pgrid, 256, 0, stream>>>(x, y, Wk, bk, Wq, bq, Wv, bv, Qw, Kw, Vt);
    dim3 agrid(S_ / 256, B_ * H_);
    attn_kernel<<<agrid, 512, 0, stream>>>(Qw, Kw, Vt, attnbuf);
    ln_kernel<<<(B_ * S_) / 4, 256, 0, stream>>>(attnbuf, y, gamma, beta, (float*)d_out);
}

// Round 9
// 156.647 us; speedup vs baseline: 1.2926x; 1.0220x over previous
//
#include <hip/hip_runtime.h>
#include <hip/hip_bf16.h>

#define B_  2
#define S_  4096
#define H_  8
#define HD_ 64
#define D_  512

using bf16x8 = __attribute__((ext_vector_type(8))) short;   // 8 bf16 in 4 VGPRs
using f32x4  = __attribute__((ext_vector_type(4))) float;
using f32x16 = __attribute__((ext_vector_type(16))) float;
using u32x4  = __attribute__((ext_vector_type(4))) unsigned int;

__device__ __forceinline__ unsigned short f2bf(float f) {
    unsigned int u = __float_as_uint(f);
    u += 0x7FFFu + ((u >> 16) & 1u);   // RNE
    return (unsigned short)(u >> 16);
}

// packed f32x2 -> bf16x2 via v_cvt_pk_bf16_f32 (no builtin on gfx950; T12 recipe)
__device__ __forceinline__ unsigned int pkbf(float a, float b) {
    unsigned int r;
    asm("v_cvt_pk_bf16_f32 %0, %1, %2" : "=v"(r) : "v"(a), "v"(b));
    return r;
}

// 3-input max (T17)
__device__ __forceinline__ float m3(float a, float b, float c) {
    float r;
    asm("v_max3_f32 %0, %1, %2, %3" : "=v"(r) : "v"(a), "v"(b), "v"(c));
    return r;
}

// ---------------------------------------------------------------------------
// Kernel 1: per-head QKV projection.  grid (S/64, B*H), block 256 (4 waves)
// K[bh][s][e], Q[bh][s][e] (pre-scaled by 0.125*log2e), Vt[bh][e][s]  (bf16)
// ---------------------------------------------------------------------------
__global__ __launch_bounds__(256) void proj_kernel(
    const float* __restrict__ x,  const float* __restrict__ yy,
    const float* __restrict__ Wk, const float* __restrict__ bk,
    const float* __restrict__ Wq, const float* __restrict__ bq,
    const float* __restrict__ Wv, const float* __restrict__ bv,
    unsigned short* __restrict__ Qw, unsigned short* __restrict__ Kw,
    unsigned short* __restrict__ Vt)
{
    __shared__ __attribute__((aligned(16))) unsigned short xs[64][72];
    __shared__ __attribute__((aligned(16))) unsigned short ys[64][72];
    __shared__ __attribute__((aligned(16))) unsigned short wtk[64][72];
    __shared__ __attribute__((aligned(16))) unsigned short wtq[64][72];
    __shared__ __attribute__((aligned(16))) unsigned short wtv[64][72];
    __shared__ __attribute__((aligned(16))) unsigned short vtl[64][72];

    const int t  = threadIdx.x;
    const int s0 = blockIdx.x * 64;
    const int bh = blockIdx.y;
    const int b  = bh >> 3, h = bh & 7;

    #pragma unroll
    for (int i = 0; i < 4; ++i) {
        int id = t + 256 * i;
        int row = id >> 4, c4 = id & 15;
        size_t ga = ((size_t)(b * S_ + s0 + row)) * D_ + h * HD_ + c4 * 4;
        float4 xv = *(const float4*)(x + ga);
        float4 yv = *(const float4*)(yy + ga);
        unsigned int xl = f2bf(xv.x) | ((unsigned int)f2bf(xv.y) << 16);
        unsigned int xh = f2bf(xv.z) | ((unsigned int)f2bf(xv.w) << 16);
        unsigned int yl = f2bf(yv.x) | ((unsigned int)f2bf(yv.y) << 16);
        unsigned int yh = f2bf(yv.z) | ((unsigned int)f2bf(yv.w) << 16);
        *(uint2*)&xs[row][c4 * 4] = make_uint2(xl, xh);
        *(uint2*)&ys[row][c4 * 4] = make_uint2(yl, yh);
    }
    #pragma unroll
    for (int i = 0; i < 4; ++i) {
        int id = t + 256 * i;
        int dd = id >> 4, e4 = id & 15;
        size_t wa = (size_t)(h * HD_ + dd) * HD_ + e4 * 4;
        float4 wk4 = *(const float4*)(Wk + wa);
        float4 wq4 = *(const float4*)(Wq + wa);
        float4 wv4 = *(const float4*)(Wv + wa);
        wtk[e4*4+0][dd] = f2bf(wk4.x); wtk[e4*4+1][dd] = f2bf(wk4.y);
        wtk[e4*4+2][dd] = f2bf(wk4.z); wtk[e4*4+3][dd] = f2bf(wk4.w);
        wtq[e4*4+0][dd] = f2bf(wq4.x); wtq[e4*4+1][dd] = f2bf(wq4.y);
        wtq[e4*4+2][dd] = f2bf(wq4.z); wtq[e4*4+3][dd] = f2bf(wq4.w);
        wtv[e4*4+0][dd] = f2bf(wv4.x); wtv[e4*4+1][dd] = f2bf(wv4.y);
        wtv[e4*4+2][dd] = f2bf(wv4.z); wtv[e4*4+3][dd] = f2bf(wv4.w);
    }
    __syncthreads();

    const int lane = t & 63, w = t >> 6;
    const int g = lane >> 4, lq = lane & 15;

    bf16x8 ax[2], ay[2];
    #pragma unroll
    for (int kk = 0; kk < 2; ++kk) {
        ax[kk] = *(const bf16x8*)&xs[w*16 + lq][kk*32 + g*8];
        ay[kk] = *(const bf16x8*)&ys[w*16 + lq][kk*32 + g*8];
    }

    f32x4 ak[4], aq[4], av[4];
    #pragma unroll
    for (int n = 0; n < 4; ++n) { ak[n] = (f32x4)0.f; aq[n] = (f32x4)0.f; av[n] = (f32x4)0.f; }

    #pragma unroll
    for (int n = 0; n < 4; ++n) {
        #pragma unroll
        for (int kk = 0; kk < 2; ++kk) {
            bf16x8 bk_ = *(const bf16x8*)&wtk[n*16 + lq][kk*32 + g*8];
            ak[n] = __builtin_amdgcn_mfma_f32_16x16x32_bf16(ax[kk], bk_, ak[n], 0, 0, 0);
            bf16x8 bq_ = *(const bf16x8*)&wtq[n*16 + lq][kk*32 + g*8];
            aq[n] = __builtin_amdgcn_mfma_f32_16x16x32_bf16(ay[kk], bq_, aq[n], 0, 0, 0);
            bf16x8 bv_ = *(const bf16x8*)&wtv[n*16 + lq][kk*32 + g*8];
            av[n] = __builtin_amdgcn_mfma_f32_16x16x32_bf16(ax[kk], bv_, av[n], 0, 0, 0);
        }
    }

    const float cscale = 0.125f * 1.44269504088896340736f;
    #pragma unroll
    for (int n = 0; n < 4; ++n) {
        int e = n*16 + lq;
        float bkv = bk[h*HD_ + e], bqv = bq[h*HD_ + e], bvv = bv[h*HD_ + e];
        #pragma unroll
        for (int r = 0; r < 4; ++r) {
            int srow = w*16 + g*4 + r;
            size_t o = ((size_t)bh * S_ + s0 + srow) * HD_ + e;
            Kw[o] = f2bf(ak[n][r] + bkv);
            Qw[o] = f2bf((aq[n][r] + bqv) * cscale);
            vtl[e][srow] = f2bf(av[n][r] + bvv);
        }
    }
    __syncthreads();
    #pragma unroll
    for (int i = 0; i < 2; ++i) {
        int id = t + 256 * i;
        int e = id >> 3, c = id & 7;
        bf16x8 v = *(const bf16x8*)&vtl[e][c*8];
        *(bf16x8*)(Vt + ((size_t)bh * HD_ + e) * S_ + s0 + c*8) = v;
    }
}

// ---------------------------------------------------------------------------
// Kernel 2: flash attention, 32x32 MFMA structure.
// grid (S/128, B*H), block 256 (4 waves x 32 q-rows each), KVBLK=64.
// 512 blocks -> 2 blocks/CU -> 16 waves/CU (~44% occupancy).
// Swapped QK^T: each lane owns a full P-row for ONE q; softmax lane-local.
// -m folded into QK C-init (no per-element sub on common path, m starts 0).
// P -> PV B-fragments in-register via cvt_pk + v_permlane32_swap (T12).
// K/V LDS tiles XOR-swizzled (T2): col ^ ((row&7)*8), [64][64] bf16.
// ---------------------------------------------------------------------------
__global__ __launch_bounds__(256, 4) void attn_kernel(
    const unsigned short* __restrict__ Qw, const unsigned short* __restrict__ Kw,
    const unsigned short* __restrict__ Vt, float* __restrict__ attn)
{
    __shared__ __attribute__((aligned(16))) unsigned short ksh[64][64];
    __shared__ __attribute__((aligned(16))) unsigned short vsh[64][64];

    const int t = threadIdx.x, lane = t & 63, w = t >> 6;   // 4 waves
    const int lx = lane & 31, hi = lane >> 5;
    const int q0 = blockIdx.x * 128;
    const int bh = blockIdx.y;
    const int b  = bh >> 3, h = bh & 7;

    const unsigned short* Kb = Kw + (size_t)bh * S_ * HD_;
    const unsigned short* Vb = Vt + (size_t)bh * HD_ * S_;

    // Q B-fragments: B[k = kq*16 + hi*8 + j][col=q=lx], held all kernel
    bf16x8 qf[4];
    #pragma unroll
    for (int kq = 0; kq < 4; ++kq)
        qf[kq] = *(const bf16x8*)(Qw + ((size_t)bh*S_ + q0 + w*32 + lx)*HD_ + kq*16 + hi*8);

    bf16x8 ones;
    #pragma unroll
    for (int j = 0; j < 8; ++j) ones[j] = (short)0x3F80;

    f32x16 oaccT[2];           // O^T[d][q]: d-blocks of 32
    oaccT[0] = (f32x16)0.f; oaccT[1] = (f32x16)0.f;
    f32x16 sacc = (f32x16)0.f; // all regs hold row-sum(P) for q=lx
    float m = 0.0f;            // running max, exp2 domain (defer-max, THR=8)

    // staging: 256 threads, 2x16B chunks per tensor each (rows r0 and r0+32)
    const int r0 = t >> 3;                 // 0..31
    const int scol = (t & 7) * 8;          // 0..56
    const int swcol = scol ^ ((r0 & 7) * 8);   // T2 XOR swizzle ((r0+32)&7 == r0&7)
    bf16x8 kr0 = *(const bf16x8*)(Kb + (size_t)r0 * HD_ + scol);
    bf16x8 kr1 = *(const bf16x8*)(Kb + (size_t)(r0 + 32) * HD_ + scol);
    bf16x8 vr0 = *(const bf16x8*)(Vb + (size_t)r0 * S_ + scol);
    bf16x8 vr1 = *(const bf16x8*)(Vb + (size_t)(r0 + 32) * S_ + scol);

    for (int kt = 0; kt < 64; ++kt) {
        __syncthreads();   // prior tile's LDS reads complete
        *(bf16x8*)&ksh[r0][swcol]      = kr0;
        *(bf16x8*)&ksh[r0 + 32][swcol] = kr1;
        *(bf16x8*)&vsh[r0][swcol]      = vr0;
        *(bf16x8*)&vsh[r0 + 32][swcol] = vr1;
        __syncthreads();

        if (kt < 63) {     // prefetch next tile; consumed at next ds_write
            const int kn = (kt + 1) * 64;
            kr0 = *(const bf16x8*)(Kb + (size_t)(kn + r0) * HD_ + scol);
            kr1 = *(const bf16x8*)(Kb + (size_t)(kn + r0 + 32) * HD_ + scol);
            vr0 = *(const bf16x8*)(Vb + (size_t)r0 * S_ + kn + scol);
            vr1 = *(const bf16x8*)(Vb + (size_t)(r0 + 32) * S_ + kn + scol);
        }

        // QK^T with C-init = -m: st = raw_score - m directly
        f32x16 st[2];
        #pragma unroll
        for (int blk = 0; blk < 2; ++blk) {
            st[blk] = (f32x16)(-m);
            const int krow = blk*32 + lx;
            #pragma unroll
            for (int kq = 0; kq < 4; ++kq) {
                bf16x8 kf = *(const bf16x8*)&ksh[krow][(kq*16 + hi*8) ^ ((krow & 7)*8)];
                st[blk] = __builtin_amdgcn_mfma_f32_32x32x16_bf16(kf, qf[kq], st[blk], 0, 0, 0);
            }
        }

        // lane-local biased tile max via v_max3 tree + hi-half combine
        float ma = m3(st[0][0], st[0][1], st[0][2]);
        float mb = m3(st[1][0], st[1][1], st[1][2]);
        #pragma unroll
        for (int r = 3; r + 1 < 16; r += 2) {
            ma = m3(ma, st[0][r], st[0][r+1]);
            mb = m3(mb, st[1][r], st[1][r+1]);
        }
        float mt = m3(fmaxf(ma, st[0][15]), mb, st[1][15]);
        mt = fmaxf(mt, __shfl_xor(mt, 32));

        // defer-max: rescale only if biased max exceeds THR=8 (P <= 2^8)
        if (!__all(mt <= 8.0f)) {
            float delta = mt > 8.0f ? mt : 0.0f;
            float corr  = exp2f(-delta);
            #pragma unroll
            for (int r = 0; r < 16; ++r) {
                oaccT[0][r] *= corr; oaccT[1][r] *= corr; sacc[r] *= corr;
                st[0][r] -= delta;   st[1][r] -= delta;
            }
            m += delta;
        }

        // P = exp2(st)  (st already biased by -m)
        float p0[16], p1[16];
        #pragma unroll
        for (int r = 0; r < 16; ++r) {
            p0[r] = exp2f(st[0][r]);
            p1[r] = exp2f(st[1][r]);
        }

        // PV: build B[k=kv][col=q] fragments in-register per ks (16 kv each).
        #pragma unroll
        for (int ks = 0; ks < 4; ++ks) {
            const int u0 = (ks & 1) * 2;
            unsigned int w0, w1, w2, w3;
            if (ks < 2) {
                w0 = pkbf(p0[4*u0+0],     p0[4*u0+1]);
                w2 = pkbf(p0[4*(u0+1)+0], p0[4*(u0+1)+1]);
                w1 = pkbf(p0[4*u0+2],     p0[4*u0+3]);
                w3 = pkbf(p0[4*(u0+1)+2], p0[4*(u0+1)+3]);
            } else {
                w0 = pkbf(p1[4*u0+0],     p1[4*u0+1]);
                w2 = pkbf(p1[4*(u0+1)+0], p1[4*(u0+1)+1]);
                w1 = pkbf(p1[4*u0+2],     p1[4*u0+3]);
                w3 = pkbf(p1[4*(u0+1)+2], p1[4*(u0+1)+3]);
            }
            asm("v_permlane32_swap_b32 %0, %1" : "+v"(w0), "+v"(w2));
            asm("v_permlane32_swap_b32 %0, %1" : "+v"(w1), "+v"(w3));
            u32x4 pw; pw.x = w0; pw.y = w1; pw.z = w2; pw.w = w3;
            bf16x8 pB = __builtin_bit_cast(bf16x8, pw);

            sacc = __builtin_amdgcn_mfma_f32_32x32x16_bf16(ones, pB, sacc, 0, 0, 0);
            #pragma unroll
            for (int d0 = 0; d0 < 2; ++d0) {
                const int vrow = d0*32 + lx;
                bf16x8 vf = *(const bf16x8*)&vsh[vrow][(ks*16 + hi*8) ^ ((vrow & 7)*8)];
                oaccT[d0] = __builtin_amdgcn_mfma_f32_32x32x16_bf16(vf, pB, oaccT[d0], 0, 0, 0);
            }
        }
    }

    // epilogue: O^T[d][q=lx] / rowsum; d = d0*32 + 8u + 4hi + (reg&3)
    float inv = 1.0f / sacc[0];
    const int qrow = q0 + w*32 + lx;
    float* orow = attn + ((size_t)b * S_ + qrow) * D_ + h * HD_;
    #pragma unroll
    for (int d0 = 0; d0 < 2; ++d0)
        #pragma unroll
        for (int u = 0; u < 4; ++u) {
            float4 o4;
            o4.x = oaccT[d0][4*u+0] * inv;
            o4.y = oaccT[d0][4*u+1] * inv;
            o4.z = oaccT[d0][4*u+2] * inv;
            o4.w = oaccT[d0][4*u+3] * inv;
            *(float4*)(orow + d0*32 + 8*u + 4*hi) = o4;
        }
}

// ---------------------------------------------------------------------------
// Kernel 3: residual + LayerNorm. One wave per row of 512. grid B*S/4, block 256
// ---------------------------------------------------------------------------
__global__ __launch_bounds__(256) void ln_kernel(
    const float* __restrict__ attn, const float* __restrict__ yy,
    const float* __restrict__ gamma, const float* __restrict__ beta,
    float* __restrict__ out)
{
    const int t = threadIdx.x, lane = t & 63, w = t >> 6;
    const size_t row = (size_t)blockIdx.x * 4 + w;
    const float* ar = attn + row * D_;
    const float* yr = yy + row * D_;

    float v[8];
    #pragma unroll
    for (int i = 0; i < 2; ++i) {
        float4 a  = *(const float4*)(ar + lane*8 + i*4);
        float4 yv = *(const float4*)(yr + lane*8 + i*4);
        v[i*4+0] = a.x + yv.x; v[i*4+1] = a.y + yv.y;
        v[i*4+2] = a.z + yv.z; v[i*4+3] = a.w + yv.w;
    }
    float s = 0.f;
    #pragma unroll
    for (int j = 0; j < 8; ++j) s += v[j];
    #pragma unroll
    for (int o = 32; o >= 1; o >>= 1) s += __shfl_xor(s, o);
    float mu = s * (1.f / 512.f);
    float qs = 0.f;
    #pragma unroll
    for (int j = 0; j < 8; ++j) { float d = v[j] - mu; qs += d * d; }
    #pragma unroll
    for (int o = 32; o >= 1; o >>= 1) qs += __shfl_xor(qs, o);
    float rstd = rsqrtf(qs * (1.f / 512.f) + 1e-5f);

    #pragma unroll
    for (int i = 0; i < 2; ++i) {
        float4 gm = *(const float4*)(gamma + lane*8 + i*4);
        float4 bt = *(const float4*)(beta  + lane*8 + i*4);
        float4 o4;
        o4.x = (v[i*4+0] - mu) * rstd * gm.x + bt.x;
        o4.y = (v[i*4+1] - mu) * rstd * gm.y + bt.y;
        o4.z = (v[i*4+2] - mu) * rstd * gm.z + bt.z;
        o4.w = (v[i*4+3] - mu) * rstd * gm.w + bt.w;
        *(float4*)(out + row * D_ + lane*8 + i*4) = o4;
    }
}

extern "C" void kernel_launch(void* const* d_in, const int* in_sizes, int n_in,
                              void* d_out, int out_size, void* d_ws, size_t ws_size,
                              hipStream_t stream) {
    const float* x     = (const float*)d_in[0];
    const float* y     = (const float*)d_in[1];
    const float* Wk    = (const float*)d_in[2];
    const float* bk    = (const float*)d_in[3];
    const float* Wq    = (const float*)d_in[4];
    const float* bq    = (const float*)d_in[5];
    const float* Wv    = (const float*)d_in[6];
    const float* bv    = (const float*)d_in[7];
    const float* gamma = (const float*)d_in[8];
    const float* beta  = (const float*)d_in[9];

    const size_t NTOK = (size_t)B_ * H_ * S_ * HD_;
    unsigned short* Qw = (unsigned short*)d_ws;
    unsigned short* Kw = Qw + NTOK;
    unsigned short* Vt = Kw + NTOK;
    float* attnbuf = (float*)(Vt + NTOK);

    dim3 pgrid(S_ / 64, B_ * H_);
    proj_kernel<<<pgrid, 256, 0, stream>>>(x, y, Wk, bk, Wq, bq, Wv, bv, Qw, Kw, Vt);
    dim3 agrid(S_ / 128, B_ * H_);
    attn_kernel<<<agrid, 256, 0, stream>>>(Qw, Kw, Vt, attnbuf);
    ln_kernel<<<(B_ * S_) / 4, 256, 0, stream>>>(attnbuf, y, gamma, beta, (float*)d_out);
}